// Round 2
// baseline (628.988 us; speedup 1.0000x reference)
//
#include <hip/hip_runtime.h>
#include <hip/hip_bf16.h>

// Problem constants (reference: B=2, S=2048, d_model=1024, H=16, dk=dv=64)
#define PB 2
#define PS 2048
#define PH 16
#define PDM 1024
#define PDK 64

typedef __attribute__((ext_vector_type(8))) short short8;
typedef __attribute__((ext_vector_type(4))) float f32x4;

__device__ __forceinline__ short f2bf(float f) {
    union { float f; unsigned u; } v; v.f = f;
    unsigned r = v.u + 0x7fffu + ((v.u >> 16) & 1u);  // RNE
    return (short)(r >> 16);
}

// out[h][c][r] = bf16(in[h][r][c]); grid = nh*C blocks, block = 256.
__global__ void transcvt_kernel(const float* __restrict__ in, short* __restrict__ out,
                                int R, int C) {
    int h = blockIdx.x / C;
    int c = blockIdx.x % C;
    const float* src = in + ((size_t)h * R) * C + c;
    short* dst = out + ((size_t)h * C + c) * R;
    for (int r = threadIdx.x; r < R; r += blockDim.x)
        dst[r] = f2bf(src[(size_t)r * C]);
}

// C = A(f32, [4096][1024]) x Bw(bf16, [n=1024][k=1024] pre-transposed) + bias
// vmode 0: store bf16 out[((b*16+h)*2048+s)*64+dk]   (head-major Q/K layout)
// vmode 1: store bf16 out[((b*16+h)*64+dk)*2048+s]   (transposed V layout)
__global__ __launch_bounds__(256) void proj_kernel(
    const float* __restrict__ A, const short* __restrict__ Bw,
    const float* __restrict__ bias, short* __restrict__ out, int vmode) {
    int wid = threadIdx.x >> 6, lane = threadIdx.x & 63;
    int lr = lane & 15, lg = lane >> 4;
    int mbase = blockIdx.x * 64 + wid * 16;
    int nbase = blockIdx.y * 64;

    f32x4 acc[4] = {};
    const float* arow = A + (size_t)(mbase + lr) * 1024 + lg * 8;
    const short* brow = Bw + (size_t)(nbase + lr) * 1024 + lg * 8;
#pragma unroll 4
    for (int kk = 0; kk < 1024; kk += 32) {
        f32x4 a0 = *(const f32x4*)(arow + kk);
        f32x4 a1 = *(const f32x4*)(arow + kk + 4);
        short8 af;
#pragma unroll
        for (int j = 0; j < 4; ++j) { af[j] = f2bf(a0[j]); af[j + 4] = f2bf(a1[j]); }
#pragma unroll
        for (int nt = 0; nt < 4; ++nt) {
            short8 bf = *(const short8*)(brow + (size_t)nt * 16 * 1024 + kk);
            acc[nt] = __builtin_amdgcn_mfma_f32_16x16x32_bf16(af, bf, acc[nt], 0, 0, 0);
        }
    }
#pragma unroll
    for (int nt = 0; nt < 4; ++nt)
#pragma unroll
        for (int r = 0; r < 4; ++r) {
            int m = mbase + lg * 4 + r;        // row = (lane>>4)*4 + r
            int n = nbase + nt * 16 + lr;      // col = lane&15
            float v = acc[nt][r] + bias[n];
            int b = m >> 11, s = m & 2047, hh = n >> 6, dk = n & 63;
            size_t idx = vmode ? ((((size_t)b * PH + hh) * 64 + dk) * PS + s)
                               : ((((size_t)b * PH + hh) * PS + s) * 64 + dk);
            out[idx] = f2bf(v);
        }
}

// Flash attention, causal. 1 wave = 16 q rows. Qh/Kh: [bh][s][64] bf16, VhT: [bh][64][s] bf16.
// Ob out: [b*2048+s][h*64+v] bf16.
__global__ __launch_bounds__(256) void attn_kernel(
    const short* __restrict__ Qh, const short* __restrict__ Kh,
    const short* __restrict__ VhT, short* __restrict__ Ob) {
    __shared__ short plds[4][16 * 32];
    int wid = threadIdx.x >> 6, lane = threadIdx.x & 63;
    int lr = lane & 15, lg = lane >> 4;
    int wg = blockIdx.x * 4 + wid;
    int qt = wg >> 5, bh = wg & 31;   // 4 waves of a block share qt -> balanced causal work
    int qbase = qt * 16;

    const short* Qp = Qh + ((size_t)bh * PS + qbase + lr) * 64 + lg * 8;
    short8 qf0 = *(const short8*)(Qp);
    short8 qf1 = *(const short8*)(Qp + 32);

    const short* Kbase = Kh + (size_t)bh * PS * 64;
    const short* Vbase = VhT + (size_t)bh * 64 * PS;

    f32x4 of[4] = {};
    float m_r[4], l_r[4];
#pragma unroll
    for (int r = 0; r < 4; ++r) { m_r[r] = -1e30f; l_r[r] = 0.f; }

    int kvend = ((qbase + 15) >> 5) << 5;   // last 32-block intersecting causal extent
    for (int kv = 0; kv <= kvend; kv += 32) {
        const short* kp = Kbase + (size_t)(kv + lr) * 64 + lg * 8;
        short8 kf00 = *(const short8*)(kp);
        short8 kf01 = *(const short8*)(kp + 32);
        short8 kf10 = *(const short8*)(kp + 16 * 64);
        short8 kf11 = *(const short8*)(kp + 16 * 64 + 32);
        f32x4 s0v = {}, s1v = {};
        s0v = __builtin_amdgcn_mfma_f32_16x16x32_bf16(qf0, kf00, s0v, 0, 0, 0);
        s0v = __builtin_amdgcn_mfma_f32_16x16x32_bf16(qf1, kf01, s0v, 0, 0, 0);
        s1v = __builtin_amdgcn_mfma_f32_16x16x32_bf16(qf0, kf10, s1v, 0, 0, 0);
        s1v = __builtin_amdgcn_mfma_f32_16x16x32_bf16(qf1, kf11, s1v, 0, 0, 0);

        float p0[4], p1[4];
#pragma unroll
        for (int r = 0; r < 4; ++r) {
            int qg = qbase + lg * 4 + r;
            float s0 = s0v[r] * 0.125f; if (kv + lr > qg)      s0 = -1e30f;
            float s1 = s1v[r] * 0.125f; if (kv + 16 + lr > qg) s1 = -1e30f;
            float mx = fmaxf(s0, s1);
            mx = fmaxf(mx, __shfl_xor(mx, 1));
            mx = fmaxf(mx, __shfl_xor(mx, 2));
            mx = fmaxf(mx, __shfl_xor(mx, 4));
            mx = fmaxf(mx, __shfl_xor(mx, 8));
            float mn = fmaxf(m_r[r], mx);
            float alpha = __expf(m_r[r] - mn);
            m_r[r] = mn;
            float e0 = __expf(s0 - mn), e1 = __expf(s1 - mn);
            p0[r] = e0; p1[r] = e1;
            float rs = e0 + e1;
            rs += __shfl_xor(rs, 1);
            rs += __shfl_xor(rs, 2);
            rs += __shfl_xor(rs, 4);
            rs += __shfl_xor(rs, 8);
            l_r[r] = l_r[r] * alpha + rs;
#pragma unroll
            for (int vt = 0; vt < 4; ++vt) of[vt][r] *= alpha;
        }
        // P (16x32) -> LDS to re-layout into A-fragment pattern
        short* pw = plds[wid];
#pragma unroll
        for (int r = 0; r < 4; ++r) {
            pw[(lg * 4 + r) * 32 + lr]      = f2bf(p0[r]);
            pw[(lg * 4 + r) * 32 + 16 + lr] = f2bf(p1[r]);
        }
        asm volatile("s_waitcnt lgkmcnt(0)" ::: "memory");
        __builtin_amdgcn_sched_barrier(0);
        short8 pa = *(const short8*)(pw + lr * 32 + lg * 8);
        const short* vp = Vbase + (size_t)lr * PS + kv + lg * 8;
#pragma unroll
        for (int vt = 0; vt < 4; ++vt) {
            short8 vf = *(const short8*)(vp + (size_t)vt * 16 * PS);
            of[vt] = __builtin_amdgcn_mfma_f32_16x16x32_bf16(pa, vf, of[vt], 0, 0, 0);
        }
    }
    int b = bh >> 4, hh = bh & 15;
#pragma unroll
    for (int vt = 0; vt < 4; ++vt)
#pragma unroll
        for (int r = 0; r < 4; ++r) {
            int qg = qbase + lg * 4 + r;
            float v = of[vt][r] / l_r[r];
            Ob[((size_t)(b * PS + qg)) * 1024 + hh * 64 + vt * 16 + lr] = f2bf(v);
        }
}

// out(f32,[4096][1024]) = A(bf16,[4096][1024]) x Bw(bf16,[n][k]) + bias[n]
__global__ __launch_bounds__(256) void outproj_kernel(
    const short* __restrict__ A, const short* __restrict__ Bw,
    const float* __restrict__ bias, float* __restrict__ out) {
    int wid = threadIdx.x >> 6, lane = threadIdx.x & 63;
    int lr = lane & 15, lg = lane >> 4;
    int mbase = blockIdx.x * 64 + wid * 16;
    int nbase = blockIdx.y * 64;

    f32x4 acc[4] = {};
    const short* arow = A + (size_t)(mbase + lr) * 1024 + lg * 8;
    const short* brow = Bw + (size_t)(nbase + lr) * 1024 + lg * 8;
#pragma unroll 4
    for (int kk = 0; kk < 1024; kk += 32) {
        short8 af = *(const short8*)(arow + kk);
#pragma unroll
        for (int nt = 0; nt < 4; ++nt) {
            short8 bf = *(const short8*)(brow + (size_t)nt * 16 * 1024 + kk);
            acc[nt] = __builtin_amdgcn_mfma_f32_16x16x32_bf16(af, bf, acc[nt], 0, 0, 0);
        }
    }
#pragma unroll
    for (int nt = 0; nt < 4; ++nt)
#pragma unroll
        for (int r = 0; r < 4; ++r) {
            int m = mbase + lg * 4 + r;
            int n = nbase + nt * 16 + lr;
            out[(size_t)m * 1024 + n] = acc[nt][r] + bias[n];
        }
}

extern "C" void kernel_launch(void* const* d_in, const int* in_sizes, int n_in,
                              void* d_out, int out_size, void* d_ws, size_t ws_size,
                              hipStream_t stream) {
    const float* Q  = (const float*)d_in[0];
    const float* K  = (const float*)d_in[1];
    const float* V  = (const float*)d_in[2];
    // d_in[3] = mask (int32 tril) -- implemented as causal predicate, not read
    const float* Wq = (const float*)d_in[4];
    const float* bq = (const float*)d_in[5];
    const float* Wk = (const float*)d_in[6];
    const float* bk = (const float*)d_in[7];
    const float* Wv = (const float*)d_in[8];
    const float* bv = (const float*)d_in[9];
    const float* Wo = (const float*)d_in[10];
    const float* bo = (const float*)d_in[11];
    float* out = (float*)d_out;

    char* ws = (char*)d_ws;
    short* WqT = (short*)(ws);                        // [16][64][1024] bf16, 2 MB
    short* WkT = (short*)(ws + (2u << 20));
    short* WvT = (short*)(ws + (4u << 20));
    short* WoT = (short*)(ws + (6u << 20));           // [1024 n][1024 k] bf16, 2 MB
    short* Qh  = (short*)(ws + (8u << 20));           // [32 bh][2048][64] bf16, 8 MB
    short* Kh  = (short*)(ws + (16u << 20));
    short* VhT = (short*)(ws + (24u << 20));          // [32 bh][64][2048] bf16, 8 MB
    short* Ob  = (short*)(ws + (32u << 20));          // [4096][1024] bf16, 8 MB

    // Weight transpose+convert
    transcvt_kernel<<<dim3(PH * PDK), 256, 0, stream>>>(Wq, WqT, PDM, PDK);
    transcvt_kernel<<<dim3(PH * PDK), 256, 0, stream>>>(Wk, WkT, PDM, PDK);
    transcvt_kernel<<<dim3(PH * PDK), 256, 0, stream>>>(Wv, WvT, PDM, PDK);
    transcvt_kernel<<<dim3(PDM), 256, 0, stream>>>(Wo, WoT, PDM, PDM);

    // Per-head projections (M=4096, N=1024, K=1024)
    dim3 pgrid(64, 16);
    proj_kernel<<<pgrid, 256, 0, stream>>>(Q, WqT, bq, Qh, 0);
    proj_kernel<<<pgrid, 256, 0, stream>>>(K, WkT, bk, Kh, 0);
    proj_kernel<<<pgrid, 256, 0, stream>>>(V, WvT, bv, VhT, 1);

    // Causal flash attention: 4096 waves (128 q-tiles x 32 bh), 4 waves/block
    attn_kernel<<<dim3(1024), 256, 0, stream>>>(Qh, Kh, VhT, Ob);

    // Output projection -> f32
    outproj_kernel<<<pgrid, 256, 0, stream>>>(Ob, WoT, bo, out);
}

// Round 3
// 337.835 us; speedup vs baseline: 1.8618x; 1.8618x over previous
//
#include <hip/hip_runtime.h>
#include <hip/hip_bf16.h>

// Problem constants (reference: B=2, S=2048, d_model=1024, H=16, dk=dv=64)
#define PB 2
#define PS 2048
#define PH 16
#define PDM 1024

typedef __attribute__((ext_vector_type(8))) short short8;
typedef __attribute__((ext_vector_type(4))) float f32x4;

__device__ __forceinline__ short f2bf(float f) {
    union { float f; unsigned u; } v; v.f = f;
    unsigned r = v.u + 0x7fffu + ((v.u >> 16) & 1u);  // RNE
    return (short)(r >> 16);
}

__device__ __forceinline__ void gload16(const void* g, void* l) {
    __builtin_amdgcn_global_load_lds(
        (const __attribute__((address_space(1))) unsigned int*)g,
        (__attribute__((address_space(3))) unsigned int*)l, 16, 0, 0);
}

// f32 -> bf16 vectorized convert (8 elems/thread)
__global__ __launch_bounds__(256) void cvt_kernel(const float* __restrict__ in,
                                                  short* __restrict__ out, int n8) {
    int i = blockIdx.x * 256 + threadIdx.x;
    if (i < n8) {
        f32x4 a = ((const f32x4*)in)[i * 2];
        f32x4 b = ((const f32x4*)in)[i * 2 + 1];
        short8 o;
#pragma unroll
        for (int j = 0; j < 4; ++j) { o[j] = f2bf(a[j]); o[j + 4] = f2bf(b[j]); }
        ((short8*)out)[i] = o;
    }
}

// LDS-tiled transpose+convert: in [nh][R][C] f32 -> out [nh][C][R] bf16.
// grid (R/64, C/64, nh), block 256.
__global__ __launch_bounds__(256) void wtrans_kernel(const float* __restrict__ in,
                                                     short* __restrict__ out, int R, int C) {
    __shared__ float t[64][65];
    int h = blockIdx.z;
    int r0 = blockIdx.x * 64, c0 = blockIdx.y * 64;
    int tr = threadIdx.x >> 2;          // 0..63
    int tc = (threadIdx.x & 3) * 16;    // 0,16,32,48
    const float* src = in + ((size_t)h * R + r0 + tr) * C + c0 + tc;
#pragma unroll
    for (int i = 0; i < 16; i += 4) {
        f32x4 v = *(const f32x4*)(src + i);
        t[tr][tc + i] = v[0]; t[tr][tc + i + 1] = v[1];
        t[tr][tc + i + 2] = v[2]; t[tr][tc + i + 3] = v[3];
    }
    __syncthreads();
    short* dst = out + ((size_t)h * C + c0 + tr) * R + r0 + tc;
    short8 o0, o1;
#pragma unroll
    for (int i = 0; i < 8; ++i) { o0[i] = f2bf(t[tc + i][tr]); o1[i] = f2bf(t[tc + 8 + i][tr]); }
    *(short8*)(dst) = o0;
    *(short8*)(dst + 8) = o1;
}

// C[M=4096][N=1024] = A(bf16 [4096][1024]) x Bw(bf16 [1024 n][1024 k]) + bias
// Tile 128x64, BK=64, 4 waves (2x2), LDS-staged via global_load_lds with
// m201-style XOR swizzle (linear LDS dest + inverse-swizzled source + swizzled read).
// MODE 0: bf16 out[((b*16+h)*2048+s)*64+dk]  (head-major Q/K)
// MODE 1: bf16 out[((b*16+h)*64+dk)*2048+s]  (transposed V)
// MODE 2: f32  out[m*1024+n] = acc + bias[n]
template<int MODE>
__global__ __launch_bounds__(256) void gemm_kernel(
    const short* __restrict__ A, const short* __restrict__ Bw,
    const float* __restrict__ bias, short* __restrict__ outb, float* __restrict__ outf) {
    __shared__ short As[128 * 64];   // 16 KB, row = 128 B (swizzled)
    __shared__ short Bs[64 * 64];    // 8 KB
    int wid = threadIdx.x >> 6, l = threadIdx.x & 63;
    int lr = l & 15, lg = l >> 4;
    int mbase = blockIdx.x * 128, nbase = blockIdx.y * 64;
    int wr = wid >> 1, wc = wid & 1;

    f32x4 acc[4][2] = {};
    int lrow8 = l >> 3;                       // 0..7
    int scol = ((l & 7) ^ lrow8) * 8;         // swizzled source col (elements)
    int rsw = (lr & 7) << 4;                  // read-side XOR (bytes)

    for (int kk = 0; kk < 1024; kk += 64) {
        // Stage A: 16 KB = 16 wave-chunks of 1 KB (4 issues/wave)
#pragma unroll
        for (int i = 0; i < 4; ++i) {
            int chunk = i * 4 + wid;                 // 0..15
            int row = chunk * 8 + lrow8;             // 0..127
            gload16(A + (size_t)(mbase + row) * 1024 + kk + scol,
                    (char*)As + chunk * 1024 + l * 16);
        }
        // Stage B: 8 KB = 8 wave-chunks (2 issues/wave)
#pragma unroll
        for (int i = 0; i < 2; ++i) {
            int chunk = i * 4 + wid;                 // 0..7
            int row = chunk * 8 + lrow8;             // 0..63
            gload16(Bw + (size_t)(nbase + row) * 1024 + kk + scol,
                    (char*)Bs + chunk * 1024 + l * 16);
        }
        __syncthreads();
#pragma unroll
        for (int ks = 0; ks < 2; ++ks) {
            short8 af[4], bf[2];
#pragma unroll
            for (int mi = 0; mi < 4; ++mi) {
                int row = wr * 64 + mi * 16 + lr;
                af[mi] = *(const short8*)((char*)As + row * 128 + ((ks * 64 + lg * 16) ^ rsw));
            }
#pragma unroll
            for (int ni = 0; ni < 2; ++ni) {
                int row = wc * 32 + ni * 16 + lr;
                bf[ni] = *(const short8*)((char*)Bs + row * 128 + ((ks * 64 + lg * 16) ^ rsw));
            }
#pragma unroll
            for (int mi = 0; mi < 4; ++mi)
#pragma unroll
                for (int ni = 0; ni < 2; ++ni)
                    acc[mi][ni] = __builtin_amdgcn_mfma_f32_16x16x32_bf16(af[mi], bf[ni], acc[mi][ni], 0, 0, 0);
        }
        __syncthreads();
    }
#pragma unroll
    for (int mi = 0; mi < 4; ++mi)
#pragma unroll
        for (int ni = 0; ni < 2; ++ni)
#pragma unroll
            for (int r = 0; r < 4; ++r) {
                int m = mbase + wr * 64 + mi * 16 + lg * 4 + r;   // row=(lane>>4)*4+r
                int n = nbase + wc * 32 + ni * 16 + lr;           // col=lane&15
                float v = acc[mi][ni][r];
                if (MODE == 2) {
                    outf[(size_t)m * 1024 + n] = v + bias[n];
                } else {
                    v += bias[n];
                    int b = m >> 11, s = m & 2047, hh = n >> 6, dk = n & 63;
                    size_t idx = (MODE == 1) ? ((((size_t)b * PH + hh) * 64 + dk) * PS + s)
                                             : ((((size_t)b * PH + hh) * PS + s) * 64 + dk);
                    outb[idx] = f2bf(v);
                }
            }
}

// Flash attention, causal. 1 wave = 16 q rows, KVBLK=64, K prefetch, defer-max,
// XOR-swizzled P-LDS. Qh/Kh: [bh][s][64] bf16, VhT: [bh][64][s] bf16.
// Grid 1024 blocks: bid = (127-qt)*8 + bh/4  (longest-first, bh-group pinned per XCD slot)
__global__ __launch_bounds__(256) void attn_kernel(
    const short* __restrict__ Qh, const short* __restrict__ Kh,
    const short* __restrict__ VhT, short* __restrict__ Ob) {
    __shared__ short plds[4][16 * 64];   // 2 KB/wave, swizzled
    int wid = threadIdx.x >> 6, lane = threadIdx.x & 63;
    int lr = lane & 15, lg = lane >> 4;
    int qt = 127 - (int)(blockIdx.x >> 3);
    int bh = (int)(blockIdx.x & 7) * 4 + wid;
    int qbase = qt * 16;

    const short* Qp = Qh + ((size_t)bh * PS + qbase + lr) * 64 + lg * 8;
    short8 qf0 = *(const short8*)(Qp);
    short8 qf1 = *(const short8*)(Qp + 32);
    const short* Kbase = Kh + (size_t)bh * PS * 64;
    const short* Vbase = VhT + (size_t)bh * 64 * PS;

    f32x4 of[4] = {};
    float m_r[4], l_r[4];
#pragma unroll
    for (int r = 0; r < 4; ++r) { m_r[r] = -1e30f; l_r[r] = 0.f; }

    int kvend = ((qbase + 15) >> 6) << 6;   // start of last 64-block needed

    short8 kf[4][2];
    {
        const short* kp = Kbase + (size_t)lr * 64 + lg * 8;
#pragma unroll
        for (int j = 0; j < 4; ++j) {
            kf[j][0] = *(const short8*)(kp + j * 1024);
            kf[j][1] = *(const short8*)(kp + j * 1024 + 32);
        }
    }
    short* pw = plds[wid];
    int swr = (lr & 7) << 4;

    for (int kv = 0; kv <= kvend; kv += 64) {
        // QK^T: S[16 q][64 k]
        f32x4 s[4];
#pragma unroll
        for (int j = 0; j < 4; ++j) {
            f32x4 z = {};
            z = __builtin_amdgcn_mfma_f32_16x16x32_bf16(qf0, kf[j][0], z, 0, 0, 0);
            z = __builtin_amdgcn_mfma_f32_16x16x32_bf16(qf1, kf[j][1], z, 0, 0, 0);
            s[j] = z;
        }
        // prefetch next K tile into kf (after last use; clamped, completes under softmax)
        {
            int kvn = kv + 64; if (kvn > kvend) kvn = kvend;
            const short* kp = Kbase + (size_t)(kvn + lr) * 64 + lg * 8;
#pragma unroll
            for (int j = 0; j < 4; ++j) {
                kf[j][0] = *(const short8*)(kp + j * 1024);
                kf[j][1] = *(const short8*)(kp + j * 1024 + 32);
            }
        }
        // issue V loads (consumed after softmax)
        short8 vf[4][2];
#pragma unroll
        for (int vt = 0; vt < 4; ++vt) {
            const short* vp = Vbase + (size_t)(vt * 16 + lr) * PS + kv + lg * 8;
            vf[vt][0] = *(const short8*)(vp);
            vf[vt][1] = *(const short8*)(vp + 32);
        }
        // online softmax (rows lg*4+r, cols 16j+lr), defer-max THR=8
#pragma unroll
        for (int r = 0; r < 4; ++r) {
            int row = lg * 4 + r;
            int qg = qbase + row;
            float t0 = (kv + lr      <= qg) ? s[0][r] * 0.125f : -1e30f;
            float t1 = (kv + 16 + lr <= qg) ? s[1][r] * 0.125f : -1e30f;
            float t2 = (kv + 32 + lr <= qg) ? s[2][r] * 0.125f : -1e30f;
            float t3 = (kv + 48 + lr <= qg) ? s[3][r] * 0.125f : -1e30f;
            float mx = fmaxf(fmaxf(t0, t1), fmaxf(t2, t3));
            mx = fmaxf(mx, __shfl_xor(mx, 1));
            mx = fmaxf(mx, __shfl_xor(mx, 2));
            mx = fmaxf(mx, __shfl_xor(mx, 4));
            mx = fmaxf(mx, __shfl_xor(mx, 8));
            if (!__all(mx <= m_r[r] + 8.f)) {
                float mn = fmaxf(m_r[r], mx);
                float al = __expf(m_r[r] - mn);
                m_r[r] = mn;
                l_r[r] *= al;
#pragma unroll
                for (int vt = 0; vt < 4; ++vt) of[vt][r] *= al;
            }
            float e0 = __expf(t0 - m_r[r]);
            float e1 = __expf(t1 - m_r[r]);
            float e2 = __expf(t2 - m_r[r]);
            float e3 = __expf(t3 - m_r[r]);
            float rs = (e0 + e1) + (e2 + e3);
            rs += __shfl_xor(rs, 1);
            rs += __shfl_xor(rs, 2);
            rs += __shfl_xor(rs, 4);
            rs += __shfl_xor(rs, 8);
            l_r[r] += rs;
            int sw = (row & 7) << 4;
            char* base = (char*)pw + row * 128;
            *(short*)(base + ((lr * 2)      ^ sw)) = f2bf(e0);
            *(short*)(base + ((32 + lr * 2) ^ sw)) = f2bf(e1);
            *(short*)(base + ((64 + lr * 2) ^ sw)) = f2bf(e2);
            *(short*)(base + ((96 + lr * 2) ^ sw)) = f2bf(e3);
        }
        asm volatile("s_waitcnt lgkmcnt(0)" ::: "memory");
        __builtin_amdgcn_sched_barrier(0);
        short8 pa0 = *(const short8*)((char*)pw + lr * 128 + ((lg * 16) ^ swr));
        short8 pa1 = *(const short8*)((char*)pw + lr * 128 + ((64 + lg * 16) ^ swr));
#pragma unroll
        for (int vt = 0; vt < 4; ++vt) {
            of[vt] = __builtin_amdgcn_mfma_f32_16x16x32_bf16(pa0, vf[vt][0], of[vt], 0, 0, 0);
            of[vt] = __builtin_amdgcn_mfma_f32_16x16x32_bf16(pa1, vf[vt][1], of[vt], 0, 0, 0);
        }
    }
    int b = bh >> 4, hh = bh & 15;
#pragma unroll
    for (int vt = 0; vt < 4; ++vt)
#pragma unroll
        for (int r = 0; r < 4; ++r) {
            int qg = qbase + lg * 4 + r;
            Ob[((size_t)(b * PS + qg)) * 1024 + hh * 64 + vt * 16 + lr] = f2bf(of[vt][r] / l_r[r]);
        }
}

extern "C" void kernel_launch(void* const* d_in, const int* in_sizes, int n_in,
                              void* d_out, int out_size, void* d_ws, size_t ws_size,
                              hipStream_t stream) {
    const float* Q  = (const float*)d_in[0];
    const float* K  = (const float*)d_in[1];
    const float* V  = (const float*)d_in[2];
    // d_in[3] = mask (int32 tril) -- implemented as causal predicate, not read
    const float* Wq = (const float*)d_in[4];
    const float* bq = (const float*)d_in[5];
    const float* Wk = (const float*)d_in[6];
    const float* bk = (const float*)d_in[7];
    const float* Wv = (const float*)d_in[8];
    const float* bv = (const float*)d_in[9];
    const float* Wo = (const float*)d_in[10];
    const float* bo = (const float*)d_in[11];
    float* out = (float*)d_out;

    char* ws = (char*)d_ws;
    short* WqT = (short*)(ws);                 // [16][64][1024] bf16, 2 MB
    short* WkT = (short*)(ws + (2u << 20));
    short* WvT = (short*)(ws + (4u << 20));
    short* WoT = (short*)(ws + (6u << 20));    // [1024 n][1024 k] bf16, 2 MB
    short* Qh  = (short*)(ws + (8u << 20));    // [32 bh][2048][64] bf16, 8 MB
    short* Kh  = (short*)(ws + (16u << 20));
    short* VhT = (short*)(ws + (24u << 20));   // [32 bh][64][2048] bf16, 8 MB
    short* Ob  = (short*)(ws + (32u << 20));   // [4096][1024] bf16, 8 MB (also Abf)
    short* Abf = Ob;                           // time-shared: activations bf16 before attn

    // Weight transposes (LDS-tiled, coalesced both sides)
    wtrans_kernel<<<dim3(16, 1, 16), 256, 0, stream>>>(Wq, WqT, PDM, 64);
    wtrans_kernel<<<dim3(16, 1, 16), 256, 0, stream>>>(Wk, WkT, PDM, 64);
    wtrans_kernel<<<dim3(16, 1, 16), 256, 0, stream>>>(Wv, WvT, PDM, 64);
    wtrans_kernel<<<dim3(16, 16, 1), 256, 0, stream>>>(Wo, WoT, PDM, PDM);

    const int n8 = PB * PS * PDM / 8;          // 524288
    dim3 ggrid(32, 16);                        // (4096/128, 1024/64)

    cvt_kernel<<<dim3(n8 / 256), 256, 0, stream>>>(Q, Abf, n8);
    gemm_kernel<0><<<ggrid, 256, 0, stream>>>(Abf, WqT, bq, Qh, nullptr);
    cvt_kernel<<<dim3(n8 / 256), 256, 0, stream>>>(K, Abf, n8);
    gemm_kernel<0><<<ggrid, 256, 0, stream>>>(Abf, WkT, bk, Kh, nullptr);
    cvt_kernel<<<dim3(n8 / 256), 256, 0, stream>>>(V, Abf, n8);
    gemm_kernel<1><<<ggrid, 256, 0, stream>>>(Abf, WvT, bv, VhT, nullptr);

    // Causal flash attention: 4096 waves, longest-qt-first, bh-grouped for L2
    attn_kernel<<<dim3(1024), 256, 0, stream>>>(Qh, Kh, VhT, Ob);

    // Output projection -> f32
    gemm_kernel<2><<<ggrid, 256, 0, stream>>>(Ob, WoT, bo, nullptr, out);
}

// Round 4
// 336.121 us; speedup vs baseline: 1.8713x; 1.0051x over previous
//
#include <hip/hip_runtime.h>
#include <hip/hip_bf16.h>

// Problem constants (reference: B=2, S=2048, d_model=1024, H=16, dk=dv=64)
#define PB 2
#define PS 2048
#define PH 16
#define PDM 1024

typedef __attribute__((ext_vector_type(8))) short short8;
typedef __attribute__((ext_vector_type(4))) float f32x4;

__device__ __forceinline__ short f2bf(float f) {
    union { float f; unsigned u; } v; v.f = f;
    unsigned r = v.u + 0x7fffu + ((v.u >> 16) & 1u);  // RNE
    return (short)(r >> 16);
}

__device__ __forceinline__ void gload16(const void* g, void* l) {
    __builtin_amdgcn_global_load_lds(
        (const __attribute__((address_space(1))) unsigned int*)g,
        (__attribute__((address_space(3))) unsigned int*)l, 16, 0, 0);
}

// f32 -> bf16 vectorized convert (8 elems/thread)
__global__ __launch_bounds__(256) void cvt_kernel(const float* __restrict__ in,
                                                  short* __restrict__ out, int n8) {
    int i = blockIdx.x * 256 + threadIdx.x;
    if (i < n8) {
        f32x4 a = ((const f32x4*)in)[i * 2];
        f32x4 b = ((const f32x4*)in)[i * 2 + 1];
        short8 o;
#pragma unroll
        for (int j = 0; j < 4; ++j) { o[j] = f2bf(a[j]); o[j + 4] = f2bf(b[j]); }
        ((short8*)out)[i] = o;
    }
}

// LDS-tiled transpose+convert: in [nh][R][C] f32 -> out [nh][C][R] bf16.
__global__ __launch_bounds__(256) void wtrans_kernel(const float* __restrict__ in,
                                                     short* __restrict__ out, int R, int C) {
    __shared__ float t[64][65];
    int h = blockIdx.z;
    int r0 = blockIdx.x * 64, c0 = blockIdx.y * 64;
    int tr = threadIdx.x >> 2;          // 0..63
    int tc = (threadIdx.x & 3) * 16;    // 0,16,32,48
    const float* src = in + ((size_t)h * R + r0 + tr) * C + c0 + tc;
#pragma unroll
    for (int i = 0; i < 16; i += 4) {
        f32x4 v = *(const f32x4*)(src + i);
        t[tr][tc + i] = v[0]; t[tr][tc + i + 1] = v[1];
        t[tr][tc + i + 2] = v[2]; t[tr][tc + i + 3] = v[3];
    }
    __syncthreads();
    short* dst = out + ((size_t)h * C + c0 + tr) * R + r0 + tc;
    short8 o0, o1;
#pragma unroll
    for (int i = 0; i < 8; ++i) { o0[i] = f2bf(t[tc + i][tr]); o1[i] = f2bf(t[tc + 8 + i][tr]); }
    *(short8*)(dst) = o0;
    *(short8*)(dst + 8) = o1;
}

// C[4096][1024] = A(bf16) x Bw(bf16 [n][k]) + bias, 2-phase double-buffered LDS.
// MODE 0: bf16 out[((b*16+h)*2048+s)*64+dk] * scale  (head-major Q/K)
// MODE 1: bf16 out[((b*16+h)*64+dk)*2048+s]          (transposed V)
// MODE 2: f32  out[m*1024+n]
template<int MODE>
__global__ __launch_bounds__(256) void gemm_kernel(
    const short* __restrict__ A, const short* __restrict__ Bw,
    const float* __restrict__ bias, short* __restrict__ outb, float* __restrict__ outf,
    float scale) {
    __shared__ short As[2][128 * 64];   // 2 x 16 KB
    __shared__ short Bs[2][64 * 64];    // 2 x 8 KB
    int wid = threadIdx.x >> 6, l = threadIdx.x & 63;
    int lr = l & 15, lg = l >> 4;
    int mbase = blockIdx.x * 128, nbase = blockIdx.y * 64;
    int wr = wid >> 1, wc = wid & 1;

    f32x4 acc[4][2] = {};
    int lrow8 = l >> 3;                       // 0..7
    int scol = ((l & 7) ^ lrow8) * 8;         // swizzled source col (elements)
    int rsw = (lr & 7) << 4;                  // read-side XOR (bytes)

#define STAGE(buf, kk)                                                              \
    {                                                                               \
        _Pragma("unroll")                                                           \
        for (int i = 0; i < 4; ++i) {                                               \
            int chunk = i * 4 + wid;                                                \
            gload16(A + (size_t)(mbase + chunk * 8 + lrow8) * 1024 + (kk) + scol,   \
                    (char*)As[buf] + chunk * 1024 + l * 16);                        \
        }                                                                           \
        _Pragma("unroll")                                                           \
        for (int i = 0; i < 2; ++i) {                                               \
            int chunk = i * 4 + wid;                                                \
            gload16(Bw + (size_t)(nbase + chunk * 8 + lrow8) * 1024 + (kk) + scol,  \
                    (char*)Bs[buf] + chunk * 1024 + l * 16);                        \
        }                                                                           \
    }

    STAGE(0, 0);
    int cur = 0;
    for (int t = 0; t < 16; ++t) {
        asm volatile("s_waitcnt vmcnt(0)" ::: "memory");
        __syncthreads();
        if (t < 15) STAGE(cur ^ 1, (t + 1) * 64);
#pragma unroll
        for (int ks = 0; ks < 2; ++ks) {
            short8 af[4], bf[2];
#pragma unroll
            for (int mi = 0; mi < 4; ++mi) {
                int row = wr * 64 + mi * 16 + lr;
                af[mi] = *(const short8*)((char*)As[cur] + row * 128 + ((ks * 64 + lg * 16) ^ rsw));
            }
#pragma unroll
            for (int ni = 0; ni < 2; ++ni) {
                int row = wc * 32 + ni * 16 + lr;
                bf[ni] = *(const short8*)((char*)Bs[cur] + row * 128 + ((ks * 64 + lg * 16) ^ rsw));
            }
            __builtin_amdgcn_s_setprio(1);
#pragma unroll
            for (int mi = 0; mi < 4; ++mi)
#pragma unroll
                for (int ni = 0; ni < 2; ++ni)
                    acc[mi][ni] = __builtin_amdgcn_mfma_f32_16x16x32_bf16(af[mi], bf[ni], acc[mi][ni], 0, 0, 0);
            __builtin_amdgcn_s_setprio(0);
        }
        cur ^= 1;
    }
#undef STAGE
#pragma unroll
    for (int mi = 0; mi < 4; ++mi)
#pragma unroll
        for (int ni = 0; ni < 2; ++ni)
#pragma unroll
            for (int r = 0; r < 4; ++r) {
                int m = mbase + wr * 64 + mi * 16 + lg * 4 + r;   // row=(lane>>4)*4+r
                int n = nbase + wc * 32 + ni * 16 + lr;           // col=lane&15
                float v = acc[mi][ni][r] + bias[n];
                if (MODE == 2) {
                    outf[(size_t)m * 1024 + n] = v;
                } else {
                    v *= scale;
                    int b = m >> 11, s = m & 2047, hh = n >> 6, dk = n & 63;
                    size_t idx = (MODE == 1) ? ((((size_t)b * PH + hh) * 64 + dk) * PS + s)
                                             : ((((size_t)b * PH + hh) * PS + s) * 64 + dk);
                    outb[idx] = f2bf(v);
                }
            }
}

// Flash attention, causal, SWAPPED QK^T (lane owns one q-row's k-slice).
// Qh (pre-scaled by 0.125) / Kh: [bh][s][64] bf16, VhT: [bh][64][s] bf16.
// 1 wave = 16 q rows, KVBLK=64. Grid: bid = (127-qt)*8 + bhgrp.
__global__ __launch_bounds__(256) void attn_kernel(
    const short* __restrict__ Qh, const short* __restrict__ Kh,
    const short* __restrict__ VhT, short* __restrict__ Ob) {
    __shared__ short plds[4][16 * 64];   // 2 KB/wave, XOR-swizzled rows
    int wid = threadIdx.x >> 6, lane = threadIdx.x & 63;
    int lr = lane & 15, lg = lane >> 4;
    int qt = 127 - (int)(blockIdx.x >> 3);
    int bh = (int)(blockIdx.x & 7) * 4 + wid;
    int qbase = qt * 16;

    const short* Qp = Qh + ((size_t)bh * PS + qbase + lr) * 64 + lg * 8;
    short8 qf0 = *(const short8*)(Qp);
    short8 qf1 = *(const short8*)(Qp + 32);
    const short* Kbase = Kh + (size_t)bh * PS * 64;
    const short* Vbase = VhT + (size_t)bh * 64 * PS;

    f32x4 of[4] = {};
    float m_r = -1e30f, l_r = 0.f;      // per-lane state for q = qbase + lr
    int kvend = ((qbase + 15) >> 6) << 6;

    short8 kf[4][2];
    {
        const short* kp = Kbase + (size_t)lr * 64 + lg * 8;
#pragma unroll
        for (int j = 0; j < 4; ++j) {
            kf[j][0] = *(const short8*)(kp + j * 1024);
            kf[j][1] = *(const short8*)(kp + j * 1024 + 32);
        }
    }
    short* pw = plds[wid];
    int swr = (lr & 7) << 4;

    for (int kv = 0;; kv += 64) {
        bool last = (kv == kvend);
        // QK^T swapped: s[j] holds S[k = kv+16j+4lg+reg][q = qbase+lr]
        f32x4 s[4];
        __builtin_amdgcn_s_setprio(1);
#pragma unroll
        for (int j = 0; j < 4; ++j) {
            f32x4 z = {};
            z = __builtin_amdgcn_mfma_f32_16x16x32_bf16(kf[j][0], qf0, z, 0, 0, 0);
            z = __builtin_amdgcn_mfma_f32_16x16x32_bf16(kf[j][1], qf1, z, 0, 0, 0);
            s[j] = z;
        }
        __builtin_amdgcn_s_setprio(0);
        // prefetch next K tile (hidden under softmax)
        if (!last) {
            const short* kp = Kbase + (size_t)(kv + 64 + lr) * 64 + lg * 8;
#pragma unroll
            for (int j = 0; j < 4; ++j) {
                kf[j][0] = *(const short8*)(kp + j * 1024);
                kf[j][1] = *(const short8*)(kp + j * 1024 + 32);
            }
        }
        // V loads (consumed after softmax)
        short8 vf[4][2];
#pragma unroll
        for (int vt = 0; vt < 4; ++vt) {
            const short* vp = Vbase + (size_t)(vt * 16 + lr) * PS + kv + lg * 8;
            vf[vt][0] = *(const short8*)(vp);
            vf[vt][1] = *(const short8*)(vp + 32);
        }
        // causal mask: final block only
        if (last) {
            int q = qbase + lr;
#pragma unroll
            for (int j = 0; j < 4; ++j) {
                int kb = kv + j * 16 + lg * 4;
#pragma unroll
                for (int g = 0; g < 4; ++g)
                    if (kb + g > q) s[j][g] = -1e30f;
            }
        }
        // row max: in-lane tree (16 values) + 2 shuffles across lg groups
        float mx;
        {
            float a0 = fmaxf(fmaxf(s[0][0], s[0][1]), fmaxf(s[0][2], s[0][3]));
            float a1 = fmaxf(fmaxf(s[1][0], s[1][1]), fmaxf(s[1][2], s[1][3]));
            float a2 = fmaxf(fmaxf(s[2][0], s[2][1]), fmaxf(s[2][2], s[2][3]));
            float a3 = fmaxf(fmaxf(s[3][0], s[3][1]), fmaxf(s[3][2], s[3][3]));
            mx = fmaxf(fmaxf(a0, a1), fmaxf(a2, a3));
        }
        mx = fmaxf(mx, __shfl_xor(mx, 16));
        mx = fmaxf(mx, __shfl_xor(mx, 32));
        // defer-max (T13, THR=8)
        if (!__all(mx <= m_r + 8.f)) {
            float mn = fmaxf(m_r, mx);
            float al = __expf(m_r - mn);
            m_r = mn;
            l_r *= al;
#pragma unroll
            for (int r = 0; r < 4; ++r) {
                float ab = __shfl(al, lg * 4 + r);   // q-row lg*4+r lives at lane lr=lg*4+r
#pragma unroll
                for (int vt = 0; vt < 4; ++vt) of[vt][r] *= ab;
            }
        }
        // exp + sum + pack P (bf16 pairs) + LDS write
        float rs = 0.f;
#pragma unroll
        for (int j = 0; j < 4; ++j) {
            float e0 = __expf(s[j][0] - m_r);
            float e1 = __expf(s[j][1] - m_r);
            float e2 = __expf(s[j][2] - m_r);
            float e3 = __expf(s[j][3] - m_r);
            rs += (e0 + e1) + (e2 + e3);
            unsigned p0, p1;
            asm("v_cvt_pk_bf16_f32 %0, %1, %2" : "=v"(p0) : "v"(e0), "v"(e1));
            asm("v_cvt_pk_bf16_f32 %0, %1, %2" : "=v"(p1) : "v"(e2), "v"(e3));
            uint2 u; u.x = p0; u.y = p1;
            *(uint2*)((char*)pw + lr * 128 + ((j * 32 + lg * 8) ^ swr)) = u;
        }
        rs += __shfl_xor(rs, 16);
        rs += __shfl_xor(rs, 32);
        l_r += rs;
        asm volatile("s_waitcnt lgkmcnt(0)" ::: "memory");
        __builtin_amdgcn_sched_barrier(0);
        short8 pa0 = *(const short8*)((char*)pw + lr * 128 + ((lg * 16) ^ swr));
        short8 pa1 = *(const short8*)((char*)pw + lr * 128 + ((64 + lg * 16) ^ swr));
        __builtin_amdgcn_s_setprio(1);
#pragma unroll
        for (int vt = 0; vt < 4; ++vt) {
            of[vt] = __builtin_amdgcn_mfma_f32_16x16x32_bf16(pa0, vf[vt][0], of[vt], 0, 0, 0);
            of[vt] = __builtin_amdgcn_mfma_f32_16x16x32_bf16(pa1, vf[vt][1], of[vt], 0, 0, 0);
        }
        __builtin_amdgcn_s_setprio(0);
        if (last) break;
    }
    int b = bh >> 4, hh = bh & 15;
    float linv[4];
#pragma unroll
    for (int r = 0; r < 4; ++r) linv[r] = 1.f / __shfl(l_r, lg * 4 + r);
#pragma unroll
    for (int vt = 0; vt < 4; ++vt)
#pragma unroll
        for (int r = 0; r < 4; ++r) {
            int qg = qbase + lg * 4 + r;
            Ob[((size_t)(b * PS + qg)) * 1024 + hh * 64 + vt * 16 + lr] = f2bf(of[vt][r] * linv[r]);
        }
}

extern "C" void kernel_launch(void* const* d_in, const int* in_sizes, int n_in,
                              void* d_out, int out_size, void* d_ws, size_t ws_size,
                              hipStream_t stream) {
    const float* Q  = (const float*)d_in[0];
    const float* K  = (const float*)d_in[1];
    const float* V  = (const float*)d_in[2];
    // d_in[3] = mask (int32 tril) -- implemented as causal predicate, not read
    const float* Wq = (const float*)d_in[4];
    const float* bq = (const float*)d_in[5];
    const float* Wk = (const float*)d_in[6];
    const float* bk = (const float*)d_in[7];
    const float* Wv = (const float*)d_in[8];
    const float* bv = (const float*)d_in[9];
    const float* Wo = (const float*)d_in[10];
    const float* bo = (const float*)d_in[11];
    float* out = (float*)d_out;

    char* ws = (char*)d_ws;
    short* WqT = (short*)(ws);                 // [16][64][1024] bf16, 2 MB
    short* WkT = (short*)(ws + (2u << 20));
    short* WvT = (short*)(ws + (4u << 20));
    short* WoT = (short*)(ws + (6u << 20));    // [1024 n][1024 k] bf16, 2 MB
    short* Qh  = (short*)(ws + (8u << 20));    // [32 bh][2048][64] bf16, 8 MB
    short* Kh  = (short*)(ws + (16u << 20));
    short* VhT = (short*)(ws + (24u << 20));   // [32 bh][64][2048] bf16, 8 MB
    short* Ob  = (short*)(ws + (32u << 20));   // [4096][1024] bf16, 8 MB (also Abf)
    short* Abf = Ob;                           // time-shared: activations bf16 before attn

    // Weight transposes (LDS-tiled, coalesced both sides)
    wtrans_kernel<<<dim3(16, 1, 16), 256, 0, stream>>>(Wq, WqT, PDM, 64);
    wtrans_kernel<<<dim3(16, 1, 16), 256, 0, stream>>>(Wk, WkT, PDM, 64);
    wtrans_kernel<<<dim3(16, 1, 16), 256, 0, stream>>>(Wv, WvT, PDM, 64);
    wtrans_kernel<<<dim3(16, 16, 1), 256, 0, stream>>>(Wo, WoT, PDM, PDM);

    const int n8 = PB * PS * PDM / 8;          // 524288
    dim3 ggrid(32, 16);                        // (4096/128, 1024/64)

    cvt_kernel<<<dim3(n8 / 256), 256, 0, stream>>>(Q, Abf, n8);
    gemm_kernel<0><<<ggrid, 256, 0, stream>>>(Abf, WqT, bq, Qh, nullptr, 0.125f);  // fold 1/sqrt(dk)
    cvt_kernel<<<dim3(n8 / 256), 256, 0, stream>>>(K, Abf, n8);
    gemm_kernel<0><<<ggrid, 256, 0, stream>>>(Abf, WkT, bk, Kh, nullptr, 1.0f);
    cvt_kernel<<<dim3(n8 / 256), 256, 0, stream>>>(V, Abf, n8);
    gemm_kernel<1><<<ggrid, 256, 0, stream>>>(Abf, WvT, bv, VhT, nullptr, 1.0f);

    // Causal flash attention: 4096 waves, longest-qt-first, bh-grouped for L2
    attn_kernel<<<dim3(1024), 256, 0, stream>>>(Qh, Kh, VhT, Ob);

    // Output projection -> f32
    gemm_kernel<2><<<ggrid, 256, 0, stream>>>(Ob, WoT, bo, nullptr, out, 1.0f);
}

// Round 9
// 256.769 us; speedup vs baseline: 2.4496x; 1.3090x over previous
//
#include <hip/hip_runtime.h>
#include <hip/hip_bf16.h>

// Problem constants (reference: B=2, S=2048, d_model=1024, H=16, dk=dv=64)
#define PB 2
#define PS 2048
#define PH 16
#define PDM 1024

typedef __attribute__((ext_vector_type(8))) short short8;
typedef __attribute__((ext_vector_type(4))) float f32x4;
typedef __attribute__((ext_vector_type(16))) float f32x16;

__device__ __forceinline__ short f2bf(float f) {
    union { float f; unsigned u; } v; v.f = f;
    unsigned r = v.u + 0x7fffu + ((v.u >> 16) & 1u);  // RNE
    return (short)(r >> 16);
}

__device__ __forceinline__ unsigned cvtpk(float a, float b) {
    unsigned r;
    asm("v_cvt_pk_bf16_f32 %0, %1, %2" : "=v"(r) : "v"(a), "v"(b));
    return r;
}

__device__ __forceinline__ float fexp2(float x) {
    float r; asm("v_exp_f32 %0, %1" : "=v"(r) : "v"(x)); return r;
}

__device__ __forceinline__ void gload16(const void* g, void* l) {
    __builtin_amdgcn_global_load_lds(
        (const __attribute__((address_space(1))) unsigned int*)g,
        (__attribute__((address_space(3))) unsigned int*)l, 16, 0, 0);
}

// f32 -> bf16 vectorized convert (8 elems/thread)
__global__ __launch_bounds__(256) void cvt_kernel(const float* __restrict__ in,
                                                  short* __restrict__ out, int n8) {
    int i = blockIdx.x * 256 + threadIdx.x;
    if (i < n8) {
        f32x4 a = ((const f32x4*)in)[i * 2];
        f32x4 b = ((const f32x4*)in)[i * 2 + 1];
        short8 o;
#pragma unroll
        for (int j = 0; j < 4; ++j) { o[j] = f2bf(a[j]); o[j + 4] = f2bf(b[j]); }
        ((short8*)out)[i] = o;
    }
}

// LDS-tiled transpose+convert: in [nh][R][C] f32 -> out [nh][C][R] bf16.
__global__ __launch_bounds__(256) void wtrans_kernel(const float* __restrict__ in,
                                                     short* __restrict__ out, int R, int C) {
    __shared__ float t[64][65];
    int h = blockIdx.z;
    int r0 = blockIdx.x * 64, c0 = blockIdx.y * 64;
    int tr = threadIdx.x >> 2;          // 0..63
    int tc = (threadIdx.x & 3) * 16;    // 0,16,32,48
    const float* src = in + ((size_t)h * R + r0 + tr) * C + c0 + tc;
#pragma unroll
    for (int i = 0; i < 16; i += 4) {
        f32x4 v = *(const f32x4*)(src + i);
        t[tr][tc + i] = v[0]; t[tr][tc + i + 1] = v[1];
        t[tr][tc + i + 2] = v[2]; t[tr][tc + i + 3] = v[3];
    }
    __syncthreads();
    short* dst = out + ((size_t)h * C + c0 + tr) * R + r0 + tc;
    short8 o0, o1;
#pragma unroll
    for (int i = 0; i < 8; ++i) { o0[i] = f2bf(t[tc + i][tr]); o1[i] = f2bf(t[tc + 8 + i][tr]); }
    *(short8*)(dst) = o0;
    *(short8*)(dst + 8) = o1;
}

// C[4096][1024] = A(bf16) x Bw(bf16 [n][k]) + bias, 2-phase double-buffered LDS.
// MODE 0: bf16 out[((b*16+h)*2048+s)*64+dk'] * scale (head-major Q/K; SWZ: dk-block ^= s&7)
// MODE 1: bf16 out[((b*16+h)*64+dk)*2048+s'] (transposed V; s-block ^= dk&7 within 64-groups)
// MODE 2: f32  out[m*1024+n]
template<int MODE, int SWZ>
__global__ __launch_bounds__(256) void gemm_kernel(
    const short* __restrict__ A, const short* __restrict__ Bw,
    const float* __restrict__ bias, short* __restrict__ outb, float* __restrict__ outf,
    float scale) {
    __shared__ short As[2][128 * 64];   // 2 x 16 KB
    __shared__ short Bs[2][64 * 64];    // 2 x 8 KB
    int wid = threadIdx.x >> 6, l = threadIdx.x & 63;
    int lr = l & 15, lg = l >> 4;
    int mbase = blockIdx.x * 128, nbase = blockIdx.y * 64;
    int wr = wid >> 1, wc = wid & 1;

    f32x4 acc[4][2] = {};
    int lrow8 = l >> 3;                       // 0..7
    int scol = ((l & 7) ^ lrow8) * 8;         // swizzled source col (elements)
    int rsw = (lr & 7) << 4;                  // read-side XOR (bytes)

#define STAGE(buf, kk)                                                              \
    {                                                                               \
        _Pragma("unroll")                                                           \
        for (int i = 0; i < 4; ++i) {                                               \
            int chunk = i * 4 + wid;                                                \
            gload16(A + (size_t)(mbase + chunk * 8 + lrow8) * 1024 + (kk) + scol,   \
                    (char*)As[buf] + chunk * 1024 + l * 16);                        \
        }                                                                           \
        _Pragma("unroll")                                                           \
        for (int i = 0; i < 2; ++i) {                                               \
            int chunk = i * 4 + wid;                                                \
            gload16(Bw + (size_t)(nbase + chunk * 8 + lrow8) * 1024 + (kk) + scol,  \
                    (char*)Bs[buf] + chunk * 1024 + l * 16);                        \
        }                                                                           \
    }

    STAGE(0, 0);
    int cur = 0;
    for (int t = 0; t < 16; ++t) {
        asm volatile("s_waitcnt vmcnt(0)" ::: "memory");
        __syncthreads();
        if (t < 15) STAGE(cur ^ 1, (t + 1) * 64);
#pragma unroll
        for (int ks = 0; ks < 2; ++ks) {
            short8 af[4], bf[2];
#pragma unroll
            for (int mi = 0; mi < 4; ++mi) {
                int row = wr * 64 + mi * 16 + lr;
                af[mi] = *(const short8*)((char*)As[cur] + row * 128 + ((ks * 64 + lg * 16) ^ rsw));
            }
#pragma unroll
            for (int ni = 0; ni < 2; ++ni) {
                int row = wc * 32 + ni * 16 + lr;
                bf[ni] = *(const short8*)((char*)Bs[cur] + row * 128 + ((ks * 64 + lg * 16) ^ rsw));
            }
            __builtin_amdgcn_s_setprio(1);
#pragma unroll
            for (int mi = 0; mi < 4; ++mi)
#pragma unroll
                for (int ni = 0; ni < 2; ++ni)
                    acc[mi][ni] = __builtin_amdgcn_mfma_f32_16x16x32_bf16(af[mi], bf[ni], acc[mi][ni], 0, 0, 0);
            __builtin_amdgcn_s_setprio(0);
        }
        cur ^= 1;
    }
#undef STAGE
#pragma unroll
    for (int mi = 0; mi < 4; ++mi)
#pragma unroll
        for (int ni = 0; ni < 2; ++ni)
#pragma unroll
            for (int r = 0; r < 4; ++r) {
                int m = mbase + wr * 64 + mi * 16 + lg * 4 + r;   // row=(lane>>4)*4+r
                int n = nbase + wc * 32 + ni * 16 + lr;           // col=lane&15
                float v = acc[mi][ni][r] + bias[n];
                if (MODE == 2) {
                    outf[(size_t)m * 1024 + n] = v;
                } else {
                    v *= scale;
                    int b = m >> 11, s = m & 2047, hh = n >> 6, dk = n & 63;
                    size_t idx;
                    if (MODE == 1) {
                        int ss = (s & ~63) | (((((s >> 3) ^ dk) & 7)) << 3) | (s & 7);
                        idx = (((size_t)b * PH + hh) * 64 + dk) * PS + ss;
                    } else {
                        int dks = SWZ ? ((dk & 7) | (((((dk >> 3) ^ s) & 7)) << 3)) : dk;
                        idx = (((size_t)b * PH + hh) * PS + s) * 64 + dks;
                    }
                    outb[idx] = f2bf(v);
                }
            }
}

// Flash attention, causal, 4 warps x 32 q-rows = 128 q/block, KVBLK=64.
// K/V double-buffered in LDS (shared by warps), XOR-swizzle pre-baked in global layout.
// Swapped QK^T (32x32 MFMA, lane owns q-col), P in registers via cvt_pk+permlane32_swap.
// Qh pre-scaled by 0.125*log2e (exp2 domain). Grid 512: bid=(15-i)*32+bh.
__global__ __launch_bounds__(256) void attn_kernel(
    const short* __restrict__ Qh, const short* __restrict__ Khs,
    const short* __restrict__ VhTs, short* __restrict__ Ob) {
    __shared__ short kbuf[2][4096];   // [64 k][64 d] rows swizzled
    __shared__ short vbuf[2][4096];   // [64 d][64 k] rows swizzled
    int tid = threadIdx.x, wid = tid >> 6;
    int l = tid & 63, lq = l & 31, h = l >> 5;
    int i = 15 - (int)(blockIdx.x >> 5);
    int bh = (int)(blockIdx.x & 31);
    int qb = i * 128;
    int qw = qb + wid * 32;
    int qmax = qw + 31;
    int myq = qw + lq;

    const short* Kb = Khs + (size_t)bh * PS * 64;
    const short* Vb = VhTs + (size_t)bh * 64 * PS;

    short8 qf[4];
    {
        const short* qp = Qh + ((size_t)bh * PS + myq) * 64 + h * 8;
#pragma unroll
        for (int c = 0; c < 4; ++c) qf[c] = *(const short8*)(qp + c * 16);
    }

    f32x16 oa0 = {}, oa1 = {};
    float m_r = -1e30f, l_r = 0.f;
    int nt = 2 * i + 2;

#define ASTAGE(buf, kv)                                                              \
    {                                                                                \
        _Pragma("unroll")                                                            \
        for (int j = 0; j < 2; ++j) {                                                \
            gload16(Kb + (size_t)((kv) + j * 32 + (tid >> 3)) * 64 + (tid & 7) * 8,  \
                    (char*)kbuf[buf] + j * 4096 + tid * 16);                         \
            gload16(Vb + (size_t)(j * 32 + (tid >> 3)) * PS + (kv) + (tid & 7) * 8,  \
                    (char*)vbuf[buf] + j * 4096 + tid * 16);                         \
        }                                                                            \
    }

    ASTAGE(0, 0);
    int cur = 0;
    for (int t = 0; t < nt; ++t) {
        int kv = t * 64;
        asm volatile("s_waitcnt vmcnt(0)" ::: "memory");
        __syncthreads();
        if (t + 1 < nt) ASTAGE(cur ^ 1, (t + 1) * 64);
        if (kv <= qmax) {
            const char* kb = (const char*)kbuf[cur];
            const char* vb = (const char*)vbuf[cur];
            // Mask needed iff this 64-wide K-tile can exceed the SMALLEST q in
            // the warp (qw), not the largest (qmax). With 32-row warps and
            // 64-wide K-tiles, odd warps' diagonal tile has kv+63 == qmax,
            // which the old (kv+63 > qmax) gate missed -> unmasked future leak.
            bool diag = (kv + 63 > qw);
            bool do1 = (kv + 32 <= qmax);
            int sw = (lq & 7);
            f32x16 s0 = {}, s1 = {};
            __builtin_amdgcn_s_setprio(1);
#pragma unroll
            for (int c = 0; c < 4; ++c) {
                short8 kf = *(const short8*)(kb + (size_t)lq * 128 + (((2 * c + h) ^ sw) * 16));
                s0 = __builtin_amdgcn_mfma_f32_32x32x16_bf16(kf, qf[c], s0, 0, 0, 0);
            }
            if (do1) {
#pragma unroll
                for (int c = 0; c < 4; ++c) {
                    short8 kf = *(const short8*)(kb + (size_t)(32 + lq) * 128 + (((2 * c + h) ^ sw) * 16));
                    s1 = __builtin_amdgcn_mfma_f32_32x32x16_bf16(kf, qf[c], s1, 0, 0, 0);
                }
            }
            __builtin_amdgcn_s_setprio(0);
            if (diag) {
#pragma unroll
                for (int r = 0; r < 16; ++r) {
                    int kg = kv + (r & 3) + 8 * (r >> 2) + 4 * h;
                    if (kg > myq) s0[r] = -1e30f;
                    if (kg + 32 > myq) s1[r] = -1e30f;
                }
            }
            float mx = -1e30f;
#pragma unroll
            for (int r = 0; r < 16; ++r) mx = fmaxf(mx, s0[r]);
            if (do1) {
#pragma unroll
                for (int r = 0; r < 16; ++r) mx = fmaxf(mx, s1[r]);
            }
            mx = fmaxf(mx, __shfl_xor(mx, 32));
            if (!__all(mx <= m_r + 8.f)) {       // defer-max (T13), exp2 domain
                float mn = fmaxf(m_r, mx);
                float al = fexp2(m_r - mn);
                m_r = mn; l_r *= al;
#pragma unroll
                for (int r = 0; r < 16; ++r) {
                    float ab = __shfl(al, (r & 3) + 8 * (r >> 2) + 4 * h);
                    oa0[r] *= ab; oa1[r] *= ab;
                }
            }
            float p0[16], p1[16];
            float rs = 0.f;
#pragma unroll
            for (int r = 0; r < 16; ++r) { p0[r] = fexp2(s0[r] - m_r); rs += p0[r]; }
            if (do1) {
#pragma unroll
                for (int r = 0; r < 16; ++r) { p1[r] = fexp2(s1[r] - m_r); rs += p1[r]; }
            } else {
#pragma unroll
                for (int r = 0; r < 16; ++r) p1[r] = 0.f;
            }
            rs += __shfl_xor(rs, 32);
            l_r += rs;
            __builtin_amdgcn_s_setprio(1);
#pragma unroll
            for (int cc = 0; cc < 4; ++cc) {
                if (cc < 2 || do1) {
                    const float* pp = (cc < 2) ? p0 : p1;
                    int b0 = (cc & 1) * 8;
                    unsigned w0 = cvtpk(pp[b0 + 0], pp[b0 + 1]);
                    unsigned w2 = cvtpk(pp[b0 + 4], pp[b0 + 5]);
                    asm("v_permlane32_swap_b32 %0, %1" : "+v"(w0), "+v"(w2));
                    unsigned w1 = cvtpk(pp[b0 + 2], pp[b0 + 3]);
                    unsigned w3 = cvtpk(pp[b0 + 6], pp[b0 + 7]);
                    asm("v_permlane32_swap_b32 %0, %1" : "+v"(w1), "+v"(w3));
                    union { unsigned u[4]; short8 s8; } pa;
                    pa.u[0] = w0; pa.u[1] = w1; pa.u[2] = w2; pa.u[3] = w3;
                    short8 vf0 = *(const short8*)(vb + (size_t)lq * 128 + (((2 * cc + h) ^ sw) * 16));
                    short8 vf1 = *(const short8*)(vb + (size_t)(32 + lq) * 128 + (((2 * cc + h) ^ sw) * 16));
                    oa0 = __builtin_amdgcn_mfma_f32_32x32x16_bf16(pa.s8, vf0, oa0, 0, 0, 0);
                    oa1 = __builtin_amdgcn_mfma_f32_32x32x16_bf16(pa.s8, vf1, oa1, 0, 0, 0);
                }
            }
            __builtin_amdgcn_s_setprio(0);
        }
        cur ^= 1;
    }
#undef ASTAGE
    float inv = 1.f / l_r;
    int b = bh >> 4, hh = bh & 15;
#pragma unroll
    for (int r = 0; r < 16; ++r) {
        int qr = (r & 3) + 8 * (r >> 2) + 4 * h;
        float li = __shfl(inv, qr);
        size_t base = ((size_t)b * PS + qb + wid * 32 + qr) * 1024 + hh * 64;
        Ob[base + lq]      = f2bf(oa0[r] * li);
        Ob[base + 32 + lq] = f2bf(oa1[r] * li);
    }
}

extern "C" void kernel_launch(void* const* d_in, const int* in_sizes, int n_in,
                              void* d_out, int out_size, void* d_ws, size_t ws_size,
                              hipStream_t stream) {
    const float* Q  = (const float*)d_in[0];
    const float* K  = (const float*)d_in[1];
    const float* V  = (const float*)d_in[2];
    // d_in[3] = mask (int32 tril) -- implemented as causal predicate, not read
    const float* Wq = (const float*)d_in[4];
    const float* bq = (const float*)d_in[5];
    const float* Wk = (const float*)d_in[6];
    const float* bk = (const float*)d_in[7];
    const float* Wv = (const float*)d_in[8];
    const float* bv = (const float*)d_in[9];
    const float* Wo = (const float*)d_in[10];
    const float* bo = (const float*)d_in[11];
    float* out = (float*)d_out;

    char* ws = (char*)d_ws;
    short* WqT = (short*)(ws);                 // [16][64][1024] bf16, 2 MB
    short* WkT = (short*)(ws + (2u << 20));
    short* WvT = (short*)(ws + (4u << 20));
    short* WoT = (short*)(ws + (6u << 20));    // [1024 n][1024 k] bf16, 2 MB
    short* Qh  = (short*)(ws + (8u << 20));    // [32 bh][2048][64] bf16, 8 MB
    short* Khs = (short*)(ws + (16u << 20));   // same, dk-block swizzled
    short* VhT = (short*)(ws + (24u << 20));   // [32 bh][64][2048] bf16, s-block swizzled
    short* Ob  = (short*)(ws + (32u << 20));   // [4096][1024] bf16, 8 MB (also Abf)
    short* Abf = Ob;                           // time-shared: activations bf16 before attn

    // Weight transposes (LDS-tiled, coalesced both sides)
    wtrans_kernel<<<dim3(16, 1, 16), 256, 0, stream>>>(Wq, WqT, PDM, 64);
    wtrans_kernel<<<dim3(16, 1, 16), 256, 0, stream>>>(Wk, WkT, PDM, 64);
    wtrans_kernel<<<dim3(16, 1, 16), 256, 0, stream>>>(Wv, WvT, PDM, 64);
    wtrans_kernel<<<dim3(16, 16, 1), 256, 0, stream>>>(Wo, WoT, PDM, PDM);

    const int n8 = PB * PS * PDM / 8;          // 524288
    dim3 ggrid(32, 16);                        // (4096/128, 1024/64)

    // Q scaled by 1/sqrt(dk) * log2(e)  (attn works in exp2 domain)
    cvt_kernel<<<dim3(n8 / 256), 256, 0, stream>>>(Q, Abf, n8);
    gemm_kernel<0, 0><<<ggrid, 256, 0, stream>>>(Abf, WqT, bq, Qh, nullptr, 0.18033688f);
    cvt_kernel<<<dim3(n8 / 256), 256, 0, stream>>>(K, Abf, n8);
    gemm_kernel<0, 1><<<ggrid, 256, 0, stream>>>(Abf, WkT, bk, Khs, nullptr, 1.0f);
    cvt_kernel<<<dim3(n8 / 256), 256, 0, stream>>>(V, Abf, n8);
    gemm_kernel<1, 0><<<ggrid, 256, 0, stream>>>(Abf, WvT, bv, VhT, nullptr, 1.0f);

    // Causal flash attention: 512 blocks (16 q-blocks x 32 bh), longest-first,
    // bh pinned per XCD slot (bid%8 == bh%8)
    attn_kernel<<<dim3(512), 256, 0, stream>>>(Qh, Khs, VhT, Ob);

    // Output projection -> f32
    gemm_kernel<2, 0><<<ggrid, 256, 0, stream>>>(Ob, WoT, bo, nullptr, out, 1.0f);
}